// Round 3
// baseline (215.180 us; speedup 1.0000x reference)
//
#include <hip/hip_runtime.h>

// GCN layer: segment_sum(x@W^T)[dst] == segment_sum(x)[dst] @ W^T (linearity).
// Round-17: 3 dispatches.
//   memset        : gcnt/ovfcnt (6 KB)
//   fused_prep    : REGISTER-CACHED edges (one ei read total); x->bf16; LDS
//                   hist; run-reserve; scatter binned[p]=(src<<6)|(dst&63).
//   sort_gather   : 512 THREADS (8 waves) per 64-node bucket — was 256; the
//                   random-gather c-loop is latency-bound at 29% occupancy,
//                   so double waves/CU (launch_bounds(512,8) pins VGPR<=64).
//                   Single-wave shfl prefix scan replaces the 12-barrier
//                   tree (barriers cost 2x at 512 threads). LDS counting
//                   sort; branchless quad gather; MFMA epilogue (AGG hi/lo
//                   bf16 planes, out = AGG@W^T + bias) on waves 0-3.
// Tier B: r14-style two-pass prep when E too large for the register cache.
// Tier D: atomic scatter + LDS linear (tiny ws / huge N).

#define DIM 64
#define BN 64             // nodes per bucket
#define BN_SHIFT 6
#define BN_MASK 63
#define NB_MAX 2048       // max buckets in LDS (8 KB)
#define PB 256            // prep blocks
#define KMAX 8            // register-cached edges per thread
#define CAPE 1536         // fixed bucket capacity (mean 1024, +16 sigma)
#define OVF_MAX 262144    // overflow list capacity (edges)
#define AGS 72            // AGG LDS row stride in bf16 (64 + 8 pad: 2-way banks)
#define SGT 512           // sort_gather threads (8 waves)

typedef __attribute__((ext_vector_type(8))) short short8;
typedef __attribute__((ext_vector_type(4))) float f32x4;

__device__ __forceinline__ unsigned short f32_to_bf16_rne(float f) {
    unsigned u = __float_as_uint(f);
    unsigned r = u + 0x7FFFu + ((u >> 16) & 1u);
    return (unsigned short)(r >> 16);
}

// pack (a,b) -> bf16x2 hi word + bf16x2 lo (residual) word, RNE (bit-ops only).
__device__ __forceinline__ void pk2(float a, float b, unsigned &ph, unsigned &pl) {
    unsigned ha = f32_to_bf16_rne(a);
    unsigned hb = f32_to_bf16_rne(b);
    ph = ha | (hb << 16);
    float fa = __uint_as_float(ha << 16);
    float fb = __uint_as_float(hb << 16);
    unsigned la = f32_to_bf16_rne(a - fa);
    unsigned lb = f32_to_bf16_rne(b - fb);
    pl = la | (lb << 16);
}

__device__ __forceinline__ f32x4 mfma16(uint4 a, uint4 b, f32x4 c) {
    return __builtin_amdgcn_mfma_f32_16x16x32_bf16(
        __builtin_bit_cast(short8, a), __builtin_bit_cast(short8, b), c, 0, 0, 0);
}

// ---------------------------------------------------------------------------
// fused_prep (register-cached): requires E <= PB*1024*KMAX.  (unchanged r15)
__global__ __launch_bounds__(1024) void fused_prep_reg_kernel(
        const float* __restrict__ x, const int* __restrict__ ei,
        ushort4* __restrict__ xb4, int* __restrict__ gcnt,
        int* __restrict__ binned, int* __restrict__ ovf,
        int* __restrict__ ovfcnt, int E, int N, int nb, int total4) {
    __shared__ int h[NB_MAX];             // hist, then cursors
    const int t = threadIdx.x;
    const int bid = blockIdx.x;

    for (int b = t; b < nb; b += 1024) h[b] = 0;
    __syncthreads();

    // load edges ONCE into registers + LDS hist
    int es[KMAX], ds[KMAX];
    #pragma unroll
    for (int k = 0; k < KMAX; ++k) {
        int e = (k * PB + bid) * 1024 + t;      // coalesced per k
        if (e < E) {
            es[k] = ei[e];
            ds[k] = ei[E + e];
            atomicAdd(&h[ds[k] >> BN_SHIFT], 1);
        } else {
            ds[k] = -1;
        }
    }

    // convert x -> bf16 (+ zero row N) — independent, overlaps hist drain
    for (int i = bid * 1024 + t; i < total4; i += PB * 1024) {
        float4 v = ((const float4*)x)[i];
        ushort4 o;
        o.x = f32_to_bf16_rne(v.x); o.y = f32_to_bf16_rne(v.y);
        o.z = f32_to_bf16_rne(v.z); o.w = f32_to_bf16_rne(v.w);
        xb4[i] = o;
    }
    if (bid == 0 && t < 16) {
        ushort4 z; z.x = 0; z.y = 0; z.z = 0; z.w = 0;
        xb4[(size_t)N * 16 + t] = z;
    }
    __syncthreads();

    // reserve a contiguous run per (block,bucket)
    for (int b = t; b < nb; b += 1024) {
        int c = h[b];
        int base = (c > 0) ? atomicAdd(&gcnt[b], c) : 0;
        h[b] = b * CAPE + base;                 // cursor
    }
    __syncthreads();

    // scatter from registers
    #pragma unroll
    for (int k = 0; k < KMAX; ++k) {
        if (ds[k] >= 0) {
            int b = ds[k] >> BN_SHIFT;
            int p = atomicAdd(&h[b], 1);
            if (p < b * CAPE + CAPE) {
                binned[p] = (es[k] << BN_SHIFT) | (ds[k] & BN_MASK);
            } else {
                int q = atomicAdd(ovfcnt, 1);
                if (q < OVF_MAX) { ovf[2 * q] = es[k]; ovf[2 * q + 1] = ds[k]; }
            }
        }
    }
}

// ---------------------------------------------------------------------------
// Tier-B prep (two-pass, r14): for E beyond the register-cache limit.
__global__ __launch_bounds__(1024) void fused_prep_kernel(
        const float* __restrict__ x, const int* __restrict__ ei,
        ushort4* __restrict__ xb4, int* __restrict__ gcnt,
        int* __restrict__ binned, int* __restrict__ ovf,
        int* __restrict__ ovfcnt, int E, int N, int nb, int total4) {
    __shared__ int h[NB_MAX];
    const int t = threadIdx.x;
    const int bid = blockIdx.x;

    for (int b = t; b < nb; b += 1024) h[b] = 0;
    __syncthreads();

    for (int i = bid * 1024 + t; i < total4; i += PB * 1024) {
        float4 v = ((const float4*)x)[i];
        ushort4 o;
        o.x = f32_to_bf16_rne(v.x); o.y = f32_to_bf16_rne(v.y);
        o.z = f32_to_bf16_rne(v.z); o.w = f32_to_bf16_rne(v.w);
        xb4[i] = o;
    }
    if (bid == 0 && t < 16) {
        ushort4 z; z.x = 0; z.y = 0; z.z = 0; z.w = 0;
        xb4[(size_t)N * 16 + t] = z;
    }

    for (int e = bid * 1024 + t; e < E; e += PB * 1024)
        atomicAdd(&h[ei[E + e] >> BN_SHIFT], 1);
    __syncthreads();

    for (int b = t; b < nb; b += 1024) {
        int c = h[b];
        int base = (c > 0) ? atomicAdd(&gcnt[b], c) : 0;
        h[b] = b * CAPE + base;
    }
    __syncthreads();

    for (int e = bid * 1024 + t; e < E; e += PB * 1024) {
        int s = ei[e];
        int d = ei[E + e];
        int b = d >> BN_SHIFT;
        int p = atomicAdd(&h[b], 1);
        if (p < b * CAPE + CAPE) {
            binned[p] = (s << BN_SHIFT) | (d & BN_MASK);
        } else {
            int q = atomicAdd(ovfcnt, 1);
            if (q < OVF_MAX) { ovf[2 * q] = s; ovf[2 * q + 1] = d; }
        }
    }
}

// ---------------------------------------------------------------------------
// Gather helpers (proven r8-r14).
__device__ __forceinline__ void acc8(float (&a)[8], const uint4& v) {
    a[0] += __uint_as_float(v.x << 16); a[1] += __uint_as_float(v.x & 0xFFFF0000u);
    a[2] += __uint_as_float(v.y << 16); a[3] += __uint_as_float(v.y & 0xFFFF0000u);
    a[4] += __uint_as_float(v.z << 16); a[5] += __uint_as_float(v.z & 0xFFFF0000u);
    a[6] += __uint_as_float(v.w << 16); a[7] += __uint_as_float(v.w & 0xFFFF0000u);
}

// pack one node row (8 f32 per lane = cols (lane&7)*8..+7) into hi/lo bf16
// LDS planes; lanes 0-7 store hi, lanes 8-15 store lo.
#define PACK_STORE(AR, ROW)                                                   \
    do {                                                                      \
        unsigned ph0, ph1, ph2, ph3, pl0, pl1, pl2, pl3;                      \
        pk2(AR[0], AR[1], ph0, pl0); pk2(AR[2], AR[3], ph1, pl1);             \
        pk2(AR[4], AR[5], ph2, pl2); pk2(AR[6], AR[7], ph3, pl3);             \
        const int dco = (lane & 7) << 3;                                      \
        if (lane < 8) {                                                       \
            uint4 v; v.x = ph0; v.y = ph1; v.z = ph2; v.w = ph3;              \
            *(uint4*)&aggh[(ROW) * AGS + dco] = v;                            \
        } else if (lane < 16) {                                               \
            uint4 v; v.x = pl0; v.y = pl1; v.z = pl2; v.w = pl3;              \
            *(uint4*)&aggl[(ROW) * AGS + dco] = v;                            \
        }                                                                     \
    } while (0)

// ---------------------------------------------------------------------------
// sort_gather (512 thr) with MFMA epilogue + inline overflow fixup.
__global__ __launch_bounds__(SGT, 8) void sort_gather_kernel(
        const unsigned short* __restrict__ xh, const float* __restrict__ xf,
        const int* __restrict__ binned, const int* __restrict__ gcnt,
        const int* __restrict__ ovf, const int* __restrict__ ovfcnt,
        const float* __restrict__ W, const float* __restrict__ bias,
        float* __restrict__ out, int N) {
    __shared__ int cnt[BN];
    __shared__ int basel[BN + 1];
    __shared__ int slds[CAPE];
    __shared__ __align__(16) unsigned short aggh[BN * AGS];  // AGG hi bf16
    __shared__ __align__(16) unsigned short aggl[BN * AGS];  // AGG lo bf16

    const int t = threadIdx.x;
    const int g = blockIdx.x;
    const int lane = t & 63;
    const int wid = t >> 6;
    const int node0 = g << BN_SHIFT;

    const int seg0 = g * CAPE;
    int len = gcnt[g];
    if (len > CAPE) len = CAPE;
    const int seg1 = seg0 + len;

    if (t < BN) cnt[t] = 0;
    __syncthreads();

    for (int i = seg0 + t; i < seg1; i += SGT)
        atomicAdd(&cnt[binned[i] & BN_MASK], 1);
    __syncthreads();

    // single-wave inclusive shfl scan over the 64 bins (wave 0 only)
    if (t < BN) {
        int myv = cnt[t];
        int v = myv;
        #pragma unroll
        for (int d = 1; d < BN; d <<= 1) {
            int u = __shfl_up(v, d, 64);
            if (t >= d) v += u;
        }
        basel[t] = v - myv;
        if (t == BN - 1) basel[BN] = v;
        cnt[t] = v - myv;                     // cursors
    }
    __syncthreads();

    for (int i = seg0 + t; i < seg1; i += SGT) {
        int v = binned[i];                    // L2-hot re-read (own 6KB window)
        int p = atomicAdd(&cnt[v & BN_MASK], 1);
        slds[p] = v >> BN_SHIFT;
    }
    __syncthreads();

    const int sub8 = lane >> 3;
    const int fb   = (lane & 7) << 3;
    const int zrow = N;
    for (int q = wid; q < (BN >> 2); q += 8) {
        const int nl = q << 2;
        int b0 = basel[nl + 0], e0 = basel[nl + 1];
        int b1 = basel[nl + 1], e1 = basel[nl + 2];
        int b2 = basel[nl + 2], e2 = basel[nl + 3];
        int b3 = basel[nl + 3], e3 = basel[nl + 4];
        int c0 = (e0 - b0 + 7) >> 3, c1 = (e1 - b1 + 7) >> 3;
        int c2 = (e2 - b2 + 7) >> 3, c3 = (e3 - b3 + 7) >> 3;
        int cmax = max(max(c0, c1), max(c2, c3));
        cmax = __builtin_amdgcn_readfirstlane(cmax);

        float A0[8] = {0.f,0.f,0.f,0.f,0.f,0.f,0.f,0.f};
        float A1[8] = {0.f,0.f,0.f,0.f,0.f,0.f,0.f,0.f};
        float A2[8] = {0.f,0.f,0.f,0.f,0.f,0.f,0.f,0.f};
        float A3[8] = {0.f,0.f,0.f,0.f,0.f,0.f,0.f,0.f};

        for (int c = 0; c < cmax; ++c) {
            const int o = (c << 3) + sub8;
            int i0 = b0 + o, i1 = b1 + o, i2 = b2 + o, i3 = b3 + o;
            int s0 = slds[min(i0, CAPE - 1)];
            int s1 = slds[min(i1, CAPE - 1)];
            int s2 = slds[min(i2, CAPE - 1)];
            int s3 = slds[min(i3, CAPE - 1)];
            s0 = (i0 < e0) ? s0 : zrow;
            s1 = (i1 < e1) ? s1 : zrow;
            s2 = (i2 < e2) ? s2 : zrow;
            s3 = (i3 < e3) ? s3 : zrow;
            uint4 v0 = *(const uint4*)(xh + (size_t)s0 * DIM + fb);
            uint4 v1 = *(const uint4*)(xh + (size_t)s1 * DIM + fb);
            uint4 v2 = *(const uint4*)(xh + (size_t)s2 * DIM + fb);
            uint4 v3 = *(const uint4*)(xh + (size_t)s3 * DIM + fb);
            acc8(A0, v0); acc8(A1, v1); acc8(A2, v2); acc8(A3, v3);
        }

        #pragma unroll
        for (int d = 8; d <= 32; d <<= 1) {
            #pragma unroll
            for (int j = 0; j < 8; ++j) {
                A0[j] += __shfl_xor(A0[j], d, 64);
                A1[j] += __shfl_xor(A1[j], d, 64);
                A2[j] += __shfl_xor(A2[j], d, 64);
                A3[j] += __shfl_xor(A3[j], d, 64);
            }
        }

        // pack AGG rows into hi/lo bf16 LDS planes (exact to ~16 mantissa bits)
        PACK_STORE(A0, nl + 0);
        PACK_STORE(A1, nl + 1);
        PACK_STORE(A2, nl + 2);
        PACK_STORE(A3, nl + 3);
    }

    __syncthreads();   // all AGG rows written

    // ---- MFMA epilogue: out[64x64] = AGG @ W^T + bias, waves 0-3 ----------
    if (wid < 4) {
        const int mbase = wid << 4;          // wave's 16 node rows
        const int l15 = lane & 15;
        const int kq  = lane >> 4;           // k-chunk 0..3

        // A frags (contiguous-8 layout: row=l&15, k=(l>>4)*8+j), hi/lo, 2 ksteps
        const unsigned short* arow_h = aggh + (mbase + l15) * AGS + (kq << 3);
        const unsigned short* arow_l = aggl + (mbase + l15) * AGS + (kq << 3);
        uint4 ah0 = *(const uint4*)(arow_h);
        uint4 ah1 = *(const uint4*)(arow_h + 32);
        uint4 al0 = *(const uint4*)(arow_l);
        uint4 al1 = *(const uint4*)(arow_l + 32);

        f32x4 acc[4];
        #pragma unroll
        for (int n = 0; n < 4; ++n) {
            float bb = bias[(n << 4) + l15];
            acc[n] = (f32x4){bb, bb, bb, bb};
        }

        #pragma unroll
        for (int n = 0; n < 4; ++n) {
            // B frag: B[k][col]=W[col][k]; col=l&15 => read W row, k-ascending
            const float* wr = W + (size_t)((n << 4) + l15) * DIM + (kq << 3);
            float4 wa = *(const float4*)(wr);
            float4 wb = *(const float4*)(wr + 4);
            float4 wc = *(const float4*)(wr + 32);
            float4 wd = *(const float4*)(wr + 36);
            uint4 bh0, bl0, bh1, bl1;
            pk2(wa.x, wa.y, bh0.x, bl0.x); pk2(wa.z, wa.w, bh0.y, bl0.y);
            pk2(wb.x, wb.y, bh0.z, bl0.z); pk2(wb.z, wb.w, bh0.w, bl0.w);
            pk2(wc.x, wc.y, bh1.x, bl1.x); pk2(wc.z, wc.w, bh1.y, bl1.y);
            pk2(wd.x, wd.y, bh1.z, bl1.z); pk2(wd.z, wd.w, bh1.w, bl1.w);
            // (Ah+Al)(Wh+Wl) ~= AhWh + AlWh + AhWl  (AlWl ~ 2^-18, dropped)
            acc[n] = mfma16(ah0, bh0, acc[n]);
            acc[n] = mfma16(al0, bh0, acc[n]);
            acc[n] = mfma16(ah0, bl0, acc[n]);
            acc[n] = mfma16(ah1, bh1, acc[n]);
            acc[n] = mfma16(al1, bh1, acc[n]);
            acc[n] = mfma16(ah1, bl1, acc[n]);
        }

        // C/D layout: col = lane&15, row = (lane>>4)*4 + i   [m89-verified]
        #pragma unroll
        for (int n = 0; n < 4; ++n) {
            #pragma unroll
            for (int i = 0; i < 4; ++i) {
                int node = node0 + mbase + (kq << 2) + i;
                if (node < N)
                    out[(size_t)node * DIM + (n << 4) + l15] = acc[n][i];
            }
        }
    }

    // inline overflow fixup: this block handles ovf edges targeting its own
    // bucket (ovfcnt is 0 in practice; cost = one L2 load + branch).
    __syncthreads();
    int oc = *ovfcnt;
    if (oc > 0) {
        if (oc > OVF_MAX) oc = OVF_MAX;
        for (int i = wid; i < oc; i += 8) {
            int s = ovf[2 * i];
            int d = ovf[2 * i + 1];
            if ((d >> BN_SHIFT) == g) {
                float v = xf[(size_t)s * DIM + lane];
                float rr0 = 0.f, rr1 = 0.f, rr2 = 0.f, rr3 = 0.f;
                #pragma unroll
                for (int k = 0; k < DIM; k += 4) {
                    rr0 += __int_as_float(__builtin_amdgcn_readlane(__float_as_int(v), k + 0)) * W[(size_t)lane * DIM + k + 0];
                    rr1 += __int_as_float(__builtin_amdgcn_readlane(__float_as_int(v), k + 1)) * W[(size_t)lane * DIM + k + 1];
                    rr2 += __int_as_float(__builtin_amdgcn_readlane(__float_as_int(v), k + 2)) * W[(size_t)lane * DIM + k + 2];
                    rr3 += __int_as_float(__builtin_amdgcn_readlane(__float_as_int(v), k + 3)) * W[(size_t)lane * DIM + k + 3];
                }
                atomicAdd(&out[(size_t)d * DIM + lane], (rr0 + rr1) + (rr2 + rr3));
            }
        }
    }
}

// ------------------- tier D: atomic scatter fallback -----------------------
__global__ void gcn_scatter_kernel(const float* __restrict__ x,
                                   const int* __restrict__ edge_index,
                                   float* __restrict__ out, int n_edges) {
    int gid = blockIdx.x * blockDim.x + threadIdx.x;
    int e = gid >> 4;
    if (e >= n_edges) return;
    int j = (gid & 15) << 2;
    int src = edge_index[e];
    int dst = edge_index[n_edges + e];
    const float4 v = *(const float4*)(x + (size_t)src * DIM + j);
    float* o = out + (size_t)dst * DIM + j;
    atomicAdd(o + 0, v.x); atomicAdd(o + 1, v.y);
    atomicAdd(o + 2, v.z); atomicAdd(o + 3, v.w);
}

__global__ void gcn_linear_inplace_kernel(float* __restrict__ out,
                                          const float* __restrict__ W,
                                          const float* __restrict__ bias,
                                          int n_nodes) {
    __shared__ float Wt[DIM * DIM];
    __shared__ float rows[4][DIM];
    int tid = threadIdx.x;
    int col = tid & 63;
    int r = tid >> 6;
    for (int i = tid; i < DIM * DIM; i += 256) {
        int c = i >> 6, k = i & 63;
        Wt[k * DIM + c] = W[i];
    }
    int row = blockIdx.x * 4 + r;
    if (row < n_nodes) rows[r][col] = out[(size_t)row * DIM + col];
    __syncthreads();
    if (row < n_nodes) {
        float a = 0.f;
        #pragma unroll
        for (int k = 0; k < DIM; ++k) a += rows[r][k] * Wt[k * DIM + col];
        out[(size_t)row * DIM + col] = a + bias[col];
    }
}

// ===========================================================================
extern "C" void kernel_launch(void* const* d_in, const int* in_sizes, int n_in,
                              void* d_out, int out_size, void* d_ws, size_t ws_size,
                              hipStream_t stream) {
    const float* x          = (const float*)d_in[0];   // [N, 64]
    const float* W          = (const float*)d_in[1];   // [64, 64]
    const float* bias       = (const float*)d_in[2];   // [64]
    const int*   edge_index = (const int*)d_in[3];     // [2, E] (int32)

    const int E = in_sizes[3] / 2;
    const int N = in_sizes[0] / DIM;
    float* out = (float*)d_out;

    const int nb = (N + BN - 1) >> BN_SHIFT;

    auto align256 = [](size_t v) { return (v + 255) & ~(size_t)255; };
    const size_t xb_b   = align256(((size_t)N + 1) * DIM * 2);   // +1 zero row
    const size_t bin_b  = align256((size_t)nb * CAPE * 4);
    const size_t cnt_b  = align256(((size_t)nb + 64) * 4);       // gcnt + ovfcnt
    const size_t ovf_b  = align256((size_t)OVF_MAX * 2 * 4);
    const size_t needA = xb_b + bin_b + cnt_b + ovf_b;

    // src must fit in 26 bits for the (src<<6)|dstlo packing
    if (nb <= NB_MAX && N < (1 << 24) && ws_size >= needA) {
        char* p = (char*)d_ws;
        ushort4* xb4 = (ushort4*)p;          p += xb_b;
        int* binned  = (int*)p;              p += bin_b;
        int* gcnt    = (int*)p;              p += cnt_b;
        int* ovf     = (int*)p;
        int* ovfcnt  = gcnt + nb;            // adjacent -> one memset

        const int total4 = N * DIM / 4;

        hipMemsetAsync(gcnt, 0, cnt_b, stream);
        if ((long long)E <= (long long)PB * 1024 * KMAX) {
            fused_prep_reg_kernel<<<PB, 1024, 0, stream>>>(
                x, edge_index, xb4, gcnt, binned, ovf, ovfcnt, E, N, nb, total4);
        } else {
            fused_prep_kernel<<<PB, 1024, 0, stream>>>(
                x, edge_index, xb4, gcnt, binned, ovf, ovfcnt, E, N, nb, total4);
        }
        sort_gather_kernel<<<nb, SGT, 0, stream>>>(
            (const unsigned short*)xb4, x, binned, gcnt, ovf, ovfcnt,
            W, bias, out, N);
    } else {
        hipMemsetAsync(d_out, 0, (size_t)out_size * sizeof(float), stream);
        long long total = (long long)E * 16;
        int grid = (int)((total + 255) / 256);
        gcn_scatter_kernel<<<grid, 256, 0, stream>>>(x, edge_index, out, E);
        int lgrid = (N + 3) / 4;
        gcn_linear_inplace_kernel<<<lgrid, 256, 0, stream>>>(out, W, bias, N);
    }
}

// Round 4
// 179.428 us; speedup vs baseline: 1.1993x; 1.1993x over previous
//
#include <hip/hip_runtime.h>

// GCN layer: segment_sum(x@W^T)[dst] == segment_sum(x)[dst] @ W^T (linearity).
// Round-18: 3 dispatches.  (r17's 512-thr + launch_bounds(512,8) pin caused
// VGPR=32 scratch spills: WRITE_SIZE 25->190MB, dur 68->110us. Reverted.)
//   memset        : gcnt/ovfcnt (6 KB)
//   fused_prep    : REGISTER-CACHED edges (one ei read total); x->bf16; LDS
//                   hist; run-reserve; scatter binned[p]=(src<<6)|(dst&63).
//   sort_gather   : 256 thr / 64-node bucket (r16 config, 68us); single-wave
//                   shfl prefix scan; LDS counting sort; gather c-loop
//                   UNROLLED x2 -> 8 independent uint4 loads in flight
//                   (latency-bound at 6 waves/SIMD LDS cap; VGPR budget to
//                   ~85 is free, r16 used only 52); MFMA epilogue (AGG hi/lo
//                   bf16 planes, out = AGG@W^T + bias).
// Tier B: r14-style two-pass prep when E too large for the register cache.
// Tier D: atomic scatter + LDS linear (tiny ws / huge N).

#define DIM 64
#define BN 64             // nodes per bucket
#define BN_SHIFT 6
#define BN_MASK 63
#define NB_MAX 2048       // max buckets in LDS (8 KB)
#define PB 256            // prep blocks
#define KMAX 8            // register-cached edges per thread
#define CAPE 1536         // fixed bucket capacity (mean 1024, +16 sigma)
#define OVF_MAX 262144    // overflow list capacity (edges)
#define AGS 72            // AGG LDS row stride in bf16 (64 + 8 pad: 2-way banks)

typedef __attribute__((ext_vector_type(8))) short short8;
typedef __attribute__((ext_vector_type(4))) float f32x4;

__device__ __forceinline__ unsigned short f32_to_bf16_rne(float f) {
    unsigned u = __float_as_uint(f);
    unsigned r = u + 0x7FFFu + ((u >> 16) & 1u);
    return (unsigned short)(r >> 16);
}

// pack (a,b) -> bf16x2 hi word + bf16x2 lo (residual) word, RNE (bit-ops only).
__device__ __forceinline__ void pk2(float a, float b, unsigned &ph, unsigned &pl) {
    unsigned ha = f32_to_bf16_rne(a);
    unsigned hb = f32_to_bf16_rne(b);
    ph = ha | (hb << 16);
    float fa = __uint_as_float(ha << 16);
    float fb = __uint_as_float(hb << 16);
    unsigned la = f32_to_bf16_rne(a - fa);
    unsigned lb = f32_to_bf16_rne(b - fb);
    pl = la | (lb << 16);
}

__device__ __forceinline__ f32x4 mfma16(uint4 a, uint4 b, f32x4 c) {
    return __builtin_amdgcn_mfma_f32_16x16x32_bf16(
        __builtin_bit_cast(short8, a), __builtin_bit_cast(short8, b), c, 0, 0, 0);
}

// ---------------------------------------------------------------------------
// fused_prep (register-cached): requires E <= PB*1024*KMAX.  (unchanged r15)
__global__ __launch_bounds__(1024) void fused_prep_reg_kernel(
        const float* __restrict__ x, const int* __restrict__ ei,
        ushort4* __restrict__ xb4, int* __restrict__ gcnt,
        int* __restrict__ binned, int* __restrict__ ovf,
        int* __restrict__ ovfcnt, int E, int N, int nb, int total4) {
    __shared__ int h[NB_MAX];             // hist, then cursors
    const int t = threadIdx.x;
    const int bid = blockIdx.x;

    for (int b = t; b < nb; b += 1024) h[b] = 0;
    __syncthreads();

    // load edges ONCE into registers + LDS hist
    int es[KMAX], ds[KMAX];
    #pragma unroll
    for (int k = 0; k < KMAX; ++k) {
        int e = (k * PB + bid) * 1024 + t;      // coalesced per k
        if (e < E) {
            es[k] = ei[e];
            ds[k] = ei[E + e];
            atomicAdd(&h[ds[k] >> BN_SHIFT], 1);
        } else {
            ds[k] = -1;
        }
    }

    // convert x -> bf16 (+ zero row N) — independent, overlaps hist drain
    for (int i = bid * 1024 + t; i < total4; i += PB * 1024) {
        float4 v = ((const float4*)x)[i];
        ushort4 o;
        o.x = f32_to_bf16_rne(v.x); o.y = f32_to_bf16_rne(v.y);
        o.z = f32_to_bf16_rne(v.z); o.w = f32_to_bf16_rne(v.w);
        xb4[i] = o;
    }
    if (bid == 0 && t < 16) {
        ushort4 z; z.x = 0; z.y = 0; z.z = 0; z.w = 0;
        xb4[(size_t)N * 16 + t] = z;
    }
    __syncthreads();

    // reserve a contiguous run per (block,bucket)
    for (int b = t; b < nb; b += 1024) {
        int c = h[b];
        int base = (c > 0) ? atomicAdd(&gcnt[b], c) : 0;
        h[b] = b * CAPE + base;                 // cursor
    }
    __syncthreads();

    // scatter from registers
    #pragma unroll
    for (int k = 0; k < KMAX; ++k) {
        if (ds[k] >= 0) {
            int b = ds[k] >> BN_SHIFT;
            int p = atomicAdd(&h[b], 1);
            if (p < b * CAPE + CAPE) {
                binned[p] = (es[k] << BN_SHIFT) | (ds[k] & BN_MASK);
            } else {
                int q = atomicAdd(ovfcnt, 1);
                if (q < OVF_MAX) { ovf[2 * q] = es[k]; ovf[2 * q + 1] = ds[k]; }
            }
        }
    }
}

// ---------------------------------------------------------------------------
// Tier-B prep (two-pass, r14): for E beyond the register-cache limit.
__global__ __launch_bounds__(1024) void fused_prep_kernel(
        const float* __restrict__ x, const int* __restrict__ ei,
        ushort4* __restrict__ xb4, int* __restrict__ gcnt,
        int* __restrict__ binned, int* __restrict__ ovf,
        int* __restrict__ ovfcnt, int E, int N, int nb, int total4) {
    __shared__ int h[NB_MAX];
    const int t = threadIdx.x;
    const int bid = blockIdx.x;

    for (int b = t; b < nb; b += 1024) h[b] = 0;
    __syncthreads();

    for (int i = bid * 1024 + t; i < total4; i += PB * 1024) {
        float4 v = ((const float4*)x)[i];
        ushort4 o;
        o.x = f32_to_bf16_rne(v.x); o.y = f32_to_bf16_rne(v.y);
        o.z = f32_to_bf16_rne(v.z); o.w = f32_to_bf16_rne(v.w);
        xb4[i] = o;
    }
    if (bid == 0 && t < 16) {
        ushort4 z; z.x = 0; z.y = 0; z.z = 0; z.w = 0;
        xb4[(size_t)N * 16 + t] = z;
    }

    for (int e = bid * 1024 + t; e < E; e += PB * 1024)
        atomicAdd(&h[ei[E + e] >> BN_SHIFT], 1);
    __syncthreads();

    for (int b = t; b < nb; b += 1024) {
        int c = h[b];
        int base = (c > 0) ? atomicAdd(&gcnt[b], c) : 0;
        h[b] = b * CAPE + base;
    }
    __syncthreads();

    for (int e = bid * 1024 + t; e < E; e += PB * 1024) {
        int s = ei[e];
        int d = ei[E + e];
        int b = d >> BN_SHIFT;
        int p = atomicAdd(&h[b], 1);
        if (p < b * CAPE + CAPE) {
            binned[p] = (s << BN_SHIFT) | (d & BN_MASK);
        } else {
            int q = atomicAdd(ovfcnt, 1);
            if (q < OVF_MAX) { ovf[2 * q] = s; ovf[2 * q + 1] = d; }
        }
    }
}

// ---------------------------------------------------------------------------
// Gather helpers (proven r8-r14).
__device__ __forceinline__ void acc8(float (&a)[8], const uint4& v) {
    a[0] += __uint_as_float(v.x << 16); a[1] += __uint_as_float(v.x & 0xFFFF0000u);
    a[2] += __uint_as_float(v.y << 16); a[3] += __uint_as_float(v.y & 0xFFFF0000u);
    a[4] += __uint_as_float(v.z << 16); a[5] += __uint_as_float(v.z & 0xFFFF0000u);
    a[6] += __uint_as_float(v.w << 16); a[7] += __uint_as_float(v.w & 0xFFFF0000u);
}

// pack one node row (8 f32 per lane = cols (lane&7)*8..+7) into hi/lo bf16
// LDS planes; lanes 0-7 store hi, lanes 8-15 store lo.
#define PACK_STORE(AR, ROW)                                                   \
    do {                                                                      \
        unsigned ph0, ph1, ph2, ph3, pl0, pl1, pl2, pl3;                      \
        pk2(AR[0], AR[1], ph0, pl0); pk2(AR[2], AR[3], ph1, pl1);             \
        pk2(AR[4], AR[5], ph2, pl2); pk2(AR[6], AR[7], ph3, pl3);             \
        const int dco = (lane & 7) << 3;                                      \
        if (lane < 8) {                                                       \
            uint4 v; v.x = ph0; v.y = ph1; v.z = ph2; v.w = ph3;              \
            *(uint4*)&aggh[(ROW) * AGS + dco] = v;                            \
        } else if (lane < 16) {                                               \
            uint4 v; v.x = pl0; v.y = pl1; v.z = pl2; v.w = pl3;              \
            *(uint4*)&aggl[(ROW) * AGS + dco] = v;                            \
        }                                                                     \
    } while (0)

// ---------------------------------------------------------------------------
// sort_gather with MFMA epilogue + inline overflow fixup.
__global__ __launch_bounds__(256) void sort_gather_kernel(
        const unsigned short* __restrict__ xh, const float* __restrict__ xf,
        const int* __restrict__ binned, const int* __restrict__ gcnt,
        const int* __restrict__ ovf, const int* __restrict__ ovfcnt,
        const float* __restrict__ W, const float* __restrict__ bias,
        float* __restrict__ out, int N) {
    __shared__ int cnt[BN];
    __shared__ int basel[BN + 1];
    __shared__ int slds[CAPE];
    __shared__ __align__(16) unsigned short aggh[BN * AGS];  // AGG hi bf16
    __shared__ __align__(16) unsigned short aggl[BN * AGS];  // AGG lo bf16

    const int t = threadIdx.x;
    const int g = blockIdx.x;
    const int lane = t & 63;
    const int wid = t >> 6;
    const int node0 = g << BN_SHIFT;

    const int seg0 = g * CAPE;
    int len = gcnt[g];
    if (len > CAPE) len = CAPE;
    const int seg1 = seg0 + len;

    if (t < BN) cnt[t] = 0;
    __syncthreads();

    for (int i = seg0 + t; i < seg1; i += 256)
        atomicAdd(&cnt[binned[i] & BN_MASK], 1);
    __syncthreads();

    // single-wave inclusive shfl scan over the 64 bins (wave 0 only)
    if (t < BN) {
        int myv = cnt[t];
        int v = myv;
        #pragma unroll
        for (int d = 1; d < BN; d <<= 1) {
            int u = __shfl_up(v, d, 64);
            if (t >= d) v += u;
        }
        basel[t] = v - myv;
        if (t == BN - 1) basel[BN] = v;
        cnt[t] = v - myv;                     // cursors
    }
    __syncthreads();

    for (int i = seg0 + t; i < seg1; i += 256) {
        int v = binned[i];                    // L2-hot re-read (own 6KB window)
        int p = atomicAdd(&cnt[v & BN_MASK], 1);
        slds[p] = v >> BN_SHIFT;
    }
    __syncthreads();

    const int sub8 = lane >> 3;
    const int fb   = (lane & 7) << 3;
    const int zrow = N;
    for (int q = wid; q < (BN >> 2); q += 4) {
        const int nl = q << 2;
        int b0 = basel[nl + 0], e0 = basel[nl + 1];
        int b1 = basel[nl + 1], e1 = basel[nl + 2];
        int b2 = basel[nl + 2], e2 = basel[nl + 3];
        int b3 = basel[nl + 3], e3 = basel[nl + 4];
        int c0 = (e0 - b0 + 7) >> 3, c1 = (e1 - b1 + 7) >> 3;
        int c2 = (e2 - b2 + 7) >> 3, c3 = (e3 - b3 + 7) >> 3;
        int cmax = max(max(c0, c1), max(c2, c3));
        cmax = __builtin_amdgcn_readfirstlane(cmax);

        float A0[8] = {0.f,0.f,0.f,0.f,0.f,0.f,0.f,0.f};
        float A1[8] = {0.f,0.f,0.f,0.f,0.f,0.f,0.f,0.f};
        float A2[8] = {0.f,0.f,0.f,0.f,0.f,0.f,0.f,0.f};
        float A3[8] = {0.f,0.f,0.f,0.f,0.f,0.f,0.f,0.f};

        // UNROLL x2: 8 independent row loads in flight per iteration
        for (int c = 0; c < cmax; c += 2) {
            const int oA = (c << 3) + sub8;
            const int oB = oA + 8;
            int i0 = b0 + oA, i1 = b1 + oA, i2 = b2 + oA, i3 = b3 + oA;
            int i4 = b0 + oB, i5 = b1 + oB, i6 = b2 + oB, i7 = b3 + oB;
            int s0 = slds[min(i0, CAPE - 1)];
            int s1 = slds[min(i1, CAPE - 1)];
            int s2 = slds[min(i2, CAPE - 1)];
            int s3 = slds[min(i3, CAPE - 1)];
            int s4 = slds[min(i4, CAPE - 1)];
            int s5 = slds[min(i5, CAPE - 1)];
            int s6 = slds[min(i6, CAPE - 1)];
            int s7 = slds[min(i7, CAPE - 1)];
            s0 = (i0 < e0) ? s0 : zrow;
            s1 = (i1 < e1) ? s1 : zrow;
            s2 = (i2 < e2) ? s2 : zrow;
            s3 = (i3 < e3) ? s3 : zrow;
            s4 = (i4 < e0) ? s4 : zrow;
            s5 = (i5 < e1) ? s5 : zrow;
            s6 = (i6 < e2) ? s6 : zrow;
            s7 = (i7 < e3) ? s7 : zrow;
            uint4 v0 = *(const uint4*)(xh + (size_t)s0 * DIM + fb);
            uint4 v1 = *(const uint4*)(xh + (size_t)s1 * DIM + fb);
            uint4 v2 = *(const uint4*)(xh + (size_t)s2 * DIM + fb);
            uint4 v3 = *(const uint4*)(xh + (size_t)s3 * DIM + fb);
            uint4 v4 = *(const uint4*)(xh + (size_t)s4 * DIM + fb);
            uint4 v5 = *(const uint4*)(xh + (size_t)s5 * DIM + fb);
            uint4 v6 = *(const uint4*)(xh + (size_t)s6 * DIM + fb);
            uint4 v7 = *(const uint4*)(xh + (size_t)s7 * DIM + fb);
            acc8(A0, v0); acc8(A1, v1); acc8(A2, v2); acc8(A3, v3);
            acc8(A0, v4); acc8(A1, v5); acc8(A2, v6); acc8(A3, v7);
        }

        #pragma unroll
        for (int d = 8; d <= 32; d <<= 1) {
            #pragma unroll
            for (int j = 0; j < 8; ++j) {
                A0[j] += __shfl_xor(A0[j], d, 64);
                A1[j] += __shfl_xor(A1[j], d, 64);
                A2[j] += __shfl_xor(A2[j], d, 64);
                A3[j] += __shfl_xor(A3[j], d, 64);
            }
        }

        // pack AGG rows into hi/lo bf16 LDS planes (exact to ~16 mantissa bits)
        PACK_STORE(A0, nl + 0);
        PACK_STORE(A1, nl + 1);
        PACK_STORE(A2, nl + 2);
        PACK_STORE(A3, nl + 3);
    }

    __syncthreads();   // all AGG rows written

    // ---- MFMA epilogue: out[64x64] = AGG @ W^T + bias, 16-row strip/wave ---
    {
        const int mbase = wid << 4;          // wave's 16 node rows
        const int l15 = lane & 15;
        const int kq  = lane >> 4;           // k-chunk 0..3

        // A frags (contiguous-8 layout: row=l&15, k=(l>>4)*8+j), hi/lo, 2 ksteps
        const unsigned short* arow_h = aggh + (mbase + l15) * AGS + (kq << 3);
        const unsigned short* arow_l = aggl + (mbase + l15) * AGS + (kq << 3);
        uint4 ah0 = *(const uint4*)(arow_h);
        uint4 ah1 = *(const uint4*)(arow_h + 32);
        uint4 al0 = *(const uint4*)(arow_l);
        uint4 al1 = *(const uint4*)(arow_l + 32);

        f32x4 acc[4];
        #pragma unroll
        for (int n = 0; n < 4; ++n) {
            float bb = bias[(n << 4) + l15];
            acc[n] = (f32x4){bb, bb, bb, bb};
        }

        #pragma unroll
        for (int n = 0; n < 4; ++n) {
            // B frag: B[k][col]=W[col][k]; col=l&15 => read W row, k-ascending
            const float* wr = W + (size_t)((n << 4) + l15) * DIM + (kq << 3);
            float4 wa = *(const float4*)(wr);
            float4 wb = *(const float4*)(wr + 4);
            float4 wc = *(const float4*)(wr + 32);
            float4 wd = *(const float4*)(wr + 36);
            uint4 bh0, bl0, bh1, bl1;
            pk2(wa.x, wa.y, bh0.x, bl0.x); pk2(wa.z, wa.w, bh0.y, bl0.y);
            pk2(wb.x, wb.y, bh0.z, bl0.z); pk2(wb.z, wb.w, bh0.w, bl0.w);
            pk2(wc.x, wc.y, bh1.x, bl1.x); pk2(wc.z, wc.w, bh1.y, bl1.y);
            pk2(wd.x, wd.y, bh1.z, bl1.z); pk2(wd.z, wd.w, bh1.w, bl1.w);
            // (Ah+Al)(Wh+Wl) ~= AhWh + AlWh + AhWl  (AlWl ~ 2^-18, dropped)
            acc[n] = mfma16(ah0, bh0, acc[n]);
            acc[n] = mfma16(al0, bh0, acc[n]);
            acc[n] = mfma16(ah0, bl0, acc[n]);
            acc[n] = mfma16(ah1, bh1, acc[n]);
            acc[n] = mfma16(al1, bh1, acc[n]);
            acc[n] = mfma16(ah1, bl1, acc[n]);
        }

        // C/D layout: col = lane&15, row = (lane>>4)*4 + i   [m89-verified]
        #pragma unroll
        for (int n = 0; n < 4; ++n) {
            #pragma unroll
            for (int i = 0; i < 4; ++i) {
                int node = node0 + mbase + (kq << 2) + i;
                if (node < N)
                    out[(size_t)node * DIM + (n << 4) + l15] = acc[n][i];
            }
        }
    }

    // inline overflow fixup: this block handles ovf edges targeting its own
    // bucket (ovfcnt is 0 in practice; cost = one L2 load + branch).
    __syncthreads();
    int oc = *ovfcnt;
    if (oc > 0) {
        if (oc > OVF_MAX) oc = OVF_MAX;
        for (int i = wid; i < oc; i += 4) {
            int s = ovf[2 * i];
            int d = ovf[2 * i + 1];
            if ((d >> BN_SHIFT) == g) {
                float v = xf[(size_t)s * DIM + lane];
                float rr0 = 0.f, rr1 = 0.f, rr2 = 0.f, rr3 = 0.f;
                #pragma unroll
                for (int k = 0; k < DIM; k += 4) {
                    rr0 += __int_as_float(__builtin_amdgcn_readlane(__float_as_int(v), k + 0)) * W[(size_t)lane * DIM + k + 0];
                    rr1 += __int_as_float(__builtin_amdgcn_readlane(__float_as_int(v), k + 1)) * W[(size_t)lane * DIM + k + 1];
                    rr2 += __int_as_float(__builtin_amdgcn_readlane(__float_as_int(v), k + 2)) * W[(size_t)lane * DIM + k + 2];
                    rr3 += __int_as_float(__builtin_amdgcn_readlane(__float_as_int(v), k + 3)) * W[(size_t)lane * DIM + k + 3];
                }
                atomicAdd(&out[(size_t)d * DIM + lane], (rr0 + rr1) + (rr2 + rr3));
            }
        }
    }
}

// ------------------- tier D: atomic scatter fallback -----------------------
__global__ void gcn_scatter_kernel(const float* __restrict__ x,
                                   const int* __restrict__ edge_index,
                                   float* __restrict__ out, int n_edges) {
    int gid = blockIdx.x * blockDim.x + threadIdx.x;
    int e = gid >> 4;
    if (e >= n_edges) return;
    int j = (gid & 15) << 2;
    int src = edge_index[e];
    int dst = edge_index[n_edges + e];
    const float4 v = *(const float4*)(x + (size_t)src * DIM + j);
    float* o = out + (size_t)dst * DIM + j;
    atomicAdd(o + 0, v.x); atomicAdd(o + 1, v.y);
    atomicAdd(o + 2, v.z); atomicAdd(o + 3, v.w);
}

__global__ void gcn_linear_inplace_kernel(float* __restrict__ out,
                                          const float* __restrict__ W,
                                          const float* __restrict__ bias,
                                          int n_nodes) {
    __shared__ float Wt[DIM * DIM];
    __shared__ float rows[4][DIM];
    int tid = threadIdx.x;
    int col = tid & 63;
    int r = tid >> 6;
    for (int i = tid; i < DIM * DIM; i += 256) {
        int c = i >> 6, k = i & 63;
        Wt[k * DIM + c] = W[i];
    }
    int row = blockIdx.x * 4 + r;
    if (row < n_nodes) rows[r][col] = out[(size_t)row * DIM + col];
    __syncthreads();
    if (row < n_nodes) {
        float a = 0.f;
        #pragma unroll
        for (int k = 0; k < DIM; ++k) a += rows[r][k] * Wt[k * DIM + col];
        out[(size_t)row * DIM + col] = a + bias[col];
    }
}

// ===========================================================================
extern "C" void kernel_launch(void* const* d_in, const int* in_sizes, int n_in,
                              void* d_out, int out_size, void* d_ws, size_t ws_size,
                              hipStream_t stream) {
    const float* x          = (const float*)d_in[0];   // [N, 64]
    const float* W          = (const float*)d_in[1];   // [64, 64]
    const float* bias       = (const float*)d_in[2];   // [64]
    const int*   edge_index = (const int*)d_in[3];     // [2, E] (int32)

    const int E = in_sizes[3] / 2;
    const int N = in_sizes[0] / DIM;
    float* out = (float*)d_out;

    const int nb = (N + BN - 1) >> BN_SHIFT;

    auto align256 = [](size_t v) { return (v + 255) & ~(size_t)255; };
    const size_t xb_b   = align256(((size_t)N + 1) * DIM * 2);   // +1 zero row
    const size_t bin_b  = align256((size_t)nb * CAPE * 4);
    const size_t cnt_b  = align256(((size_t)nb + 64) * 4);       // gcnt + ovfcnt
    const size_t ovf_b  = align256((size_t)OVF_MAX * 2 * 4);
    const size_t needA = xb_b + bin_b + cnt_b + ovf_b;

    // src must fit in 26 bits for the (src<<6)|dstlo packing
    if (nb <= NB_MAX && N < (1 << 24) && ws_size >= needA) {
        char* p = (char*)d_ws;
        ushort4* xb4 = (ushort4*)p;          p += xb_b;
        int* binned  = (int*)p;              p += bin_b;
        int* gcnt    = (int*)p;              p += cnt_b;
        int* ovf     = (int*)p;
        int* ovfcnt  = gcnt + nb;            // adjacent -> one memset

        const int total4 = N * DIM / 4;

        hipMemsetAsync(gcnt, 0, cnt_b, stream);
        if ((long long)E <= (long long)PB * 1024 * KMAX) {
            fused_prep_reg_kernel<<<PB, 1024, 0, stream>>>(
                x, edge_index, xb4, gcnt, binned, ovf, ovfcnt, E, N, nb, total4);
        } else {
            fused_prep_kernel<<<PB, 1024, 0, stream>>>(
                x, edge_index, xb4, gcnt, binned, ovf, ovfcnt, E, N, nb, total4);
        }
        sort_gather_kernel<<<nb, 256, 0, stream>>>(
            (const unsigned short*)xb4, x, binned, gcnt, ovf, ovfcnt,
            W, bias, out, N);
    } else {
        hipMemsetAsync(d_out, 0, (size_t)out_size * sizeof(float), stream);
        long long total = (long long)E * 16;
        int grid = (int)((total + 255) / 256);
        gcn_scatter_kernel<<<grid, 256, 0, stream>>>(x, edge_index, out, E);
        int lgrid = (N + 3) / 4;
        gcn_linear_inplace_kernel<<<lgrid, 256, 0, stream>>>(out, W, bias, N);
    }
}

// Round 6
// 174.571 us; speedup vs baseline: 1.2326x; 1.0278x over previous
//
#include <hip/hip_runtime.h>

// GCN layer: segment_sum(x@W^T)[dst] == segment_sum(x)[dst] @ W^T (linearity).
// Round-19 (resubmit; r5 bench was an infra failure): 3 dispatches.
//   r17 (512thr pin) -> spills, r18 (ILP x2) -> +4us: neither TLP nor ILP
//   helps => gather is L2-miss-bound (12.8MB src pool vs 4MB/XCD L2).
//   NEW: counting-sort key extended to (dst&63, src>>shift) = 1024 bins.
//   Node runs stay contiguous but internally src-tile-sorted; co-resident
//   blocks advance q-iters in phase => all blocks sweep the same ~800KB
//   src window together => window fits L2 on every XCD.
//   Gather body reverted to the r16 winner (no unroll). Occupancy held at
//   6 blocks/CU: CAPE 1536->1280 (+8sigma, overflow path intact), AGS
//   72->64 (epilogue LDS conflicts are 4 reads/thread = noise).
// Tier B: r14-style two-pass prep when E too large for the register cache.
// Tier D: atomic scatter + LDS linear (tiny ws / huge N).

#define DIM 64
#define BN 64             // nodes per bucket
#define BN_SHIFT 6
#define BN_MASK 63
#define NB_MAX 2048       // max buckets in LDS (8 KB)
#define PB 256            // prep blocks
#define KMAX 8            // register-cached edges per thread
#define CAPE 1280         // fixed bucket capacity (mean 1024, +8 sigma)
#define OVF_MAX 262144    // overflow list capacity (edges)
#define AGS 64            // AGG LDS row stride in bf16
#define NBIN 1024         // sort bins: 64 nodes x 16 src-tiles

typedef __attribute__((ext_vector_type(8))) short short8;
typedef __attribute__((ext_vector_type(4))) float f32x4;

__device__ __forceinline__ unsigned short f32_to_bf16_rne(float f) {
    unsigned u = __float_as_uint(f);
    unsigned r = u + 0x7FFFu + ((u >> 16) & 1u);
    return (unsigned short)(r >> 16);
}

// pack (a,b) -> bf16x2 hi word + bf16x2 lo (residual) word, RNE (bit-ops only).
__device__ __forceinline__ void pk2(float a, float b, unsigned &ph, unsigned &pl) {
    unsigned ha = f32_to_bf16_rne(a);
    unsigned hb = f32_to_bf16_rne(b);
    ph = ha | (hb << 16);
    float fa = __uint_as_float(ha << 16);
    float fb = __uint_as_float(hb << 16);
    unsigned la = f32_to_bf16_rne(a - fa);
    unsigned lb = f32_to_bf16_rne(b - fb);
    pl = la | (lb << 16);
}

__device__ __forceinline__ f32x4 mfma16(uint4 a, uint4 b, f32x4 c) {
    return __builtin_amdgcn_mfma_f32_16x16x32_bf16(
        __builtin_bit_cast(short8, a), __builtin_bit_cast(short8, b), c, 0, 0, 0);
}

// ---------------------------------------------------------------------------
// fused_prep (register-cached): requires E <= PB*1024*KMAX.
__global__ __launch_bounds__(1024) void fused_prep_reg_kernel(
        const float* __restrict__ x, const int* __restrict__ ei,
        ushort4* __restrict__ xb4, int* __restrict__ gcnt,
        int* __restrict__ binned, int* __restrict__ ovf,
        int* __restrict__ ovfcnt, int E, int N, int nb, int total4) {
    __shared__ int h[NB_MAX];             // hist, then cursors
    const int t = threadIdx.x;
    const int bid = blockIdx.x;

    for (int b = t; b < nb; b += 1024) h[b] = 0;
    __syncthreads();

    // load edges ONCE into registers + LDS hist
    int es[KMAX], ds[KMAX];
    #pragma unroll
    for (int k = 0; k < KMAX; ++k) {
        int e = (k * PB + bid) * 1024 + t;      // coalesced per k
        if (e < E) {
            es[k] = ei[e];
            ds[k] = ei[E + e];
            atomicAdd(&h[ds[k] >> BN_SHIFT], 1);
        } else {
            ds[k] = -1;
        }
    }

    // convert x -> bf16 (+ zero row N) — independent, overlaps hist drain
    for (int i = bid * 1024 + t; i < total4; i += PB * 1024) {
        float4 v = ((const float4*)x)[i];
        ushort4 o;
        o.x = f32_to_bf16_rne(v.x); o.y = f32_to_bf16_rne(v.y);
        o.z = f32_to_bf16_rne(v.z); o.w = f32_to_bf16_rne(v.w);
        xb4[i] = o;
    }
    if (bid == 0 && t < 16) {
        ushort4 z; z.x = 0; z.y = 0; z.z = 0; z.w = 0;
        xb4[(size_t)N * 16 + t] = z;
    }
    __syncthreads();

    // reserve a contiguous run per (block,bucket)
    for (int b = t; b < nb; b += 1024) {
        int c = h[b];
        int base = (c > 0) ? atomicAdd(&gcnt[b], c) : 0;
        h[b] = b * CAPE + base;                 // cursor
    }
    __syncthreads();

    // scatter from registers
    #pragma unroll
    for (int k = 0; k < KMAX; ++k) {
        if (ds[k] >= 0) {
            int b = ds[k] >> BN_SHIFT;
            int p = atomicAdd(&h[b], 1);
            if (p < b * CAPE + CAPE) {
                binned[p] = (es[k] << BN_SHIFT) | (ds[k] & BN_MASK);
            } else {
                int q = atomicAdd(ovfcnt, 1);
                if (q < OVF_MAX) { ovf[2 * q] = es[k]; ovf[2 * q + 1] = ds[k]; }
            }
        }
    }
}

// ---------------------------------------------------------------------------
// Tier-B prep (two-pass, r14): for E beyond the register-cache limit.
__global__ __launch_bounds__(1024) void fused_prep_kernel(
        const float* __restrict__ x, const int* __restrict__ ei,
        ushort4* __restrict__ xb4, int* __restrict__ gcnt,
        int* __restrict__ binned, int* __restrict__ ovf,
        int* __restrict__ ovfcnt, int E, int N, int nb, int total4) {
    __shared__ int h[NB_MAX];
    const int t = threadIdx.x;
    const int bid = blockIdx.x;

    for (int b = t; b < nb; b += 1024) h[b] = 0;
    __syncthreads();

    for (int i = bid * 1024 + t; i < total4; i += PB * 1024) {
        float4 v = ((const float4*)x)[i];
        ushort4 o;
        o.x = f32_to_bf16_rne(v.x); o.y = f32_to_bf16_rne(v.y);
        o.z = f32_to_bf16_rne(v.z); o.w = f32_to_bf16_rne(v.w);
        xb4[i] = o;
    }
    if (bid == 0 && t < 16) {
        ushort4 z; z.x = 0; z.y = 0; z.z = 0; z.w = 0;
        xb4[(size_t)N * 16 + t] = z;
    }

    for (int e = bid * 1024 + t; e < E; e += PB * 1024)
        atomicAdd(&h[ei[E + e] >> BN_SHIFT], 1);
    __syncthreads();

    for (int b = t; b < nb; b += 1024) {
        int c = h[b];
        int base = (c > 0) ? atomicAdd(&gcnt[b], c) : 0;
        h[b] = b * CAPE + base;
    }
    __syncthreads();

    for (int e = bid * 1024 + t; e < E; e += PB * 1024) {
        int s = ei[e];
        int d = ei[E + e];
        int b = d >> BN_SHIFT;
        int p = atomicAdd(&h[b], 1);
        if (p < b * CAPE + CAPE) {
            binned[p] = (s << BN_SHIFT) | (d & BN_MASK);
        } else {
            int q = atomicAdd(ovfcnt, 1);
            if (q < OVF_MAX) { ovf[2 * q] = s; ovf[2 * q + 1] = d; }
        }
    }
}

// ---------------------------------------------------------------------------
// Gather helpers (proven r8-r14).
__device__ __forceinline__ void acc8(float (&a)[8], const uint4& v) {
    a[0] += __uint_as_float(v.x << 16); a[1] += __uint_as_float(v.x & 0xFFFF0000u);
    a[2] += __uint_as_float(v.y << 16); a[3] += __uint_as_float(v.y & 0xFFFF0000u);
    a[4] += __uint_as_float(v.z << 16); a[5] += __uint_as_float(v.z & 0xFFFF0000u);
    a[6] += __uint_as_float(v.w << 16); a[7] += __uint_as_float(v.w & 0xFFFF0000u);
}

// pack one node row (8 f32 per lane = cols (lane&7)*8..+7) into hi/lo bf16
// LDS planes; lanes 0-7 store hi, lanes 8-15 store lo.
#define PACK_STORE(AR, ROW)                                                   \
    do {                                                                      \
        unsigned ph0, ph1, ph2, ph3, pl0, pl1, pl2, pl3;                      \
        pk2(AR[0], AR[1], ph0, pl0); pk2(AR[2], AR[3], ph1, pl1);             \
        pk2(AR[4], AR[5], ph2, pl2); pk2(AR[6], AR[7], ph3, pl3);             \
        const int dco = (lane & 7) << 3;                                      \
        if (lane < 8) {                                                       \
            uint4 v; v.x = ph0; v.y = ph1; v.z = ph2; v.w = ph3;              \
            *(uint4*)&aggh[(ROW) * AGS + dco] = v;                            \
        } else if (lane < 16) {                                               \
            uint4 v; v.x = pl0; v.y = pl1; v.z = pl2; v.w = pl3;              \
            *(uint4*)&aggl[(ROW) * AGS + dco] = v;                            \
        }                                                                     \
    } while (0)

// ---------------------------------------------------------------------------
// sort_gather: 1024-bin (node, src-tile) counting sort -> phase-coherent
// src sweep across co-resident blocks; MFMA epilogue; overflow fixup.
__global__ __launch_bounds__(256) void sort_gather_kernel(
        const unsigned short* __restrict__ xh, const float* __restrict__ xf,
        const int* __restrict__ binned, const int* __restrict__ gcnt,
        const int* __restrict__ ovf, const int* __restrict__ ovfcnt,
        const float* __restrict__ W, const float* __restrict__ bias,
        float* __restrict__ out, int N, int shift) {
    __shared__ int cnt[NBIN];             // hist, then cursors (4 KB)
    __shared__ int basel[BN + 1];
    __shared__ int wsum[4];
    __shared__ int slds[CAPE];
    __shared__ __align__(16) unsigned short aggh[BN * AGS];  // AGG hi bf16
    __shared__ __align__(16) unsigned short aggl[BN * AGS];  // AGG lo bf16

    const int t = threadIdx.x;
    const int g = blockIdx.x;
    const int lane = t & 63;
    const int wid = t >> 6;
    const int node0 = g << BN_SHIFT;

    const int seg0 = g * CAPE;
    int len = gcnt[g];
    if (len > CAPE) len = CAPE;
    const int seg1 = seg0 + len;

    for (int i = t; i < NBIN; i += 256) cnt[i] = 0;
    __syncthreads();

    // hist over (dst&63, src>>shift) keys
    for (int i = seg0 + t; i < seg1; i += 256) {
        int v = binned[i];
        int tile = min(15, (v >> BN_SHIFT) >> shift);
        atomicAdd(&cnt[((v & BN_MASK) << 4) | tile], 1);
    }
    __syncthreads();

    // block-wide exclusive scan of the 1024 bins: thread owns 4 bins
    {
        int c0 = cnt[4 * t + 0], c1 = cnt[4 * t + 1];
        int c2 = cnt[4 * t + 2], c3 = cnt[4 * t + 3];
        int s = c0 + c1 + c2 + c3;
        int incl = s;
        #pragma unroll
        for (int d = 1; d < 64; d <<= 1) {
            int u = __shfl_up(incl, d, 64);
            if (lane >= d) incl += u;
        }
        if (lane == 63) wsum[wid] = incl;
        __syncthreads();
        int woff = 0;
        for (int w = 0; w < wid; ++w) woff += wsum[w];
        int excl = woff + incl - s;
        cnt[4 * t + 0] = excl;
        cnt[4 * t + 1] = excl + c0;
        cnt[4 * t + 2] = excl + c0 + c1;
        cnt[4 * t + 3] = excl + c0 + c1 + c2;
    }
    __syncthreads();

    if (t < BN) basel[t] = cnt[t << 4];   // node start = its first tile-bin
    if (t == 0) basel[BN] = len;
    __syncthreads();

    // scatter: node runs contiguous, internally src-tile-sorted
    for (int i = seg0 + t; i < seg1; i += 256) {
        int v = binned[i];                    // L2-hot re-read (own 5KB window)
        int src = v >> BN_SHIFT;
        int tile = min(15, src >> shift);
        int p = atomicAdd(&cnt[((v & BN_MASK) << 4) | tile], 1);
        slds[p] = src;
    }
    __syncthreads();

    const int sub8 = lane >> 3;
    const int fb   = (lane & 7) << 3;
    const int zrow = N;
    for (int q = wid; q < (BN >> 2); q += 4) {
        const int nl = q << 2;
        int b0 = basel[nl + 0], e0 = basel[nl + 1];
        int b1 = basel[nl + 1], e1 = basel[nl + 2];
        int b2 = basel[nl + 2], e2 = basel[nl + 3];
        int b3 = basel[nl + 3], e3 = basel[nl + 4];
        int c0 = (e0 - b0 + 7) >> 3, c1 = (e1 - b1 + 7) >> 3;
        int c2 = (e2 - b2 + 7) >> 3, c3 = (e3 - b3 + 7) >> 3;
        int cmax = max(max(c0, c1), max(c2, c3));
        cmax = __builtin_amdgcn_readfirstlane(cmax);

        float A0[8] = {0.f,0.f,0.f,0.f,0.f,0.f,0.f,0.f};
        float A1[8] = {0.f,0.f,0.f,0.f,0.f,0.f,0.f,0.f};
        float A2[8] = {0.f,0.f,0.f,0.f,0.f,0.f,0.f,0.f};
        float A3[8] = {0.f,0.f,0.f,0.f,0.f,0.f,0.f,0.f};

        for (int c = 0; c < cmax; ++c) {
            const int o = (c << 3) + sub8;
            int i0 = b0 + o, i1 = b1 + o, i2 = b2 + o, i3 = b3 + o;
            int s0 = slds[min(i0, CAPE - 1)];
            int s1 = slds[min(i1, CAPE - 1)];
            int s2 = slds[min(i2, CAPE - 1)];
            int s3 = slds[min(i3, CAPE - 1)];
            s0 = (i0 < e0) ? s0 : zrow;
            s1 = (i1 < e1) ? s1 : zrow;
            s2 = (i2 < e2) ? s2 : zrow;
            s3 = (i3 < e3) ? s3 : zrow;
            uint4 v0 = *(const uint4*)(xh + (size_t)s0 * DIM + fb);
            uint4 v1 = *(const uint4*)(xh + (size_t)s1 * DIM + fb);
            uint4 v2 = *(const uint4*)(xh + (size_t)s2 * DIM + fb);
            uint4 v3 = *(const uint4*)(xh + (size_t)s3 * DIM + fb);
            acc8(A0, v0); acc8(A1, v1); acc8(A2, v2); acc8(A3, v3);
        }

        #pragma unroll
        for (int d = 8; d <= 32; d <<= 1) {
            #pragma unroll
            for (int j = 0; j < 8; ++j) {
                A0[j] += __shfl_xor(A0[j], d, 64);
                A1[j] += __shfl_xor(A1[j], d, 64);
                A2[j] += __shfl_xor(A2[j], d, 64);
                A3[j] += __shfl_xor(A3[j], d, 64);
            }
        }

        // pack AGG rows into hi/lo bf16 LDS planes (exact to ~16 mantissa bits)
        PACK_STORE(A0, nl + 0);
        PACK_STORE(A1, nl + 1);
        PACK_STORE(A2, nl + 2);
        PACK_STORE(A3, nl + 3);
    }

    __syncthreads();   // all AGG rows written

    // ---- MFMA epilogue: out[64x64] = AGG @ W^T + bias, 16-row strip/wave ---
    {
        const int mbase = wid << 4;          // wave's 16 node rows
        const int l15 = lane & 15;
        const int kq  = lane >> 4;           // k-chunk 0..3

        // A frags (contiguous-8 layout: row=l&15, k=(l>>4)*8+j), hi/lo, 2 ksteps
        const unsigned short* arow_h = aggh + (mbase + l15) * AGS + (kq << 3);
        const unsigned short* arow_l = aggl + (mbase + l15) * AGS + (kq << 3);
        uint4 ah0 = *(const uint4*)(arow_h);
        uint4 ah1 = *(const uint4*)(arow_h + 32);
        uint4 al0 = *(const uint4*)(arow_l);
        uint4 al1 = *(const uint4*)(arow_l + 32);

        f32x4 acc[4];
        #pragma unroll
        for (int n = 0; n < 4; ++n) {
            float bb = bias[(n << 4) + l15];
            acc[n] = (f32x4){bb, bb, bb, bb};
        }

        #pragma unroll
        for (int n = 0; n < 4; ++n) {
            // B frag: B[k][col]=W[col][k]; col=l&15 => read W row, k-ascending
            const float* wr = W + (size_t)((n << 4) + l15) * DIM + (kq << 3);
            float4 wa = *(const float4*)(wr);
            float4 wb = *(const float4*)(wr + 4);
            float4 wc = *(const float4*)(wr + 32);
            float4 wd = *(const float4*)(wr + 36);
            uint4 bh0, bl0, bh1, bl1;
            pk2(wa.x, wa.y, bh0.x, bl0.x); pk2(wa.z, wa.w, bh0.y, bl0.y);
            pk2(wb.x, wb.y, bh0.z, bl0.z); pk2(wb.z, wb.w, bh0.w, bl0.w);
            pk2(wc.x, wc.y, bh1.x, bl1.x); pk2(wc.z, wc.w, bh1.y, bl1.y);
            pk2(wd.x, wd.y, bh1.z, bl1.z); pk2(wd.z, wd.w, bh1.w, bl1.w);
            // (Ah+Al)(Wh+Wl) ~= AhWh + AlWh + AhWl  (AlWl ~ 2^-18, dropped)
            acc[n] = mfma16(ah0, bh0, acc[n]);
            acc[n] = mfma16(al0, bh0, acc[n]);
            acc[n] = mfma16(ah0, bl0, acc[n]);
            acc[n] = mfma16(ah1, bh1, acc[n]);
            acc[n] = mfma16(al1, bh1, acc[n]);
            acc[n] = mfma16(ah1, bl1, acc[n]);
        }

        // C/D layout: col = lane&15, row = (lane>>4)*4 + i   [m89-verified]
        #pragma unroll
        for (int n = 0; n < 4; ++n) {
            #pragma unroll
            for (int i = 0; i < 4; ++i) {
                int node = node0 + mbase + (kq << 2) + i;
                if (node < N)
                    out[(size_t)node * DIM + (n << 4) + l15] = acc[n][i];
            }
        }
    }

    // inline overflow fixup: this block handles ovf edges targeting its own
    // bucket (ovfcnt is 0 in practice; cost = one L2 load + branch).
    __syncthreads();
    int oc = *ovfcnt;
    if (oc > 0) {
        if (oc > OVF_MAX) oc = OVF_MAX;
        for (int i = wid; i < oc; i += 4) {
            int s = ovf[2 * i];
            int d = ovf[2 * i + 1];
            if ((d >> BN_SHIFT) == g) {
                float v = xf[(size_t)s * DIM + lane];
                float rr0 = 0.f, rr1 = 0.f, rr2 = 0.f, rr3 = 0.f;
                #pragma unroll
                for (int k = 0; k < DIM; k += 4) {
                    rr0 += __int_as_float(__builtin_amdgcn_readlane(__float_as_int(v), k + 0)) * W[(size_t)lane * DIM + k + 0];
                    rr1 += __int_as_float(__builtin_amdgcn_readlane(__float_as_int(v), k + 1)) * W[(size_t)lane * DIM + k + 1];
                    rr2 += __int_as_float(__builtin_amdgcn_readlane(__float_as_int(v), k + 2)) * W[(size_t)lane * DIM + k + 2];
                    rr3 += __int_as_float(__builtin_amdgcn_readlane(__float_as_int(v), k + 3)) * W[(size_t)lane * DIM + k + 3];
                }
                atomicAdd(&out[(size_t)d * DIM + lane], (rr0 + rr1) + (rr2 + rr3));
            }
        }
    }
}

// ------------------- tier D: atomic scatter fallback -----------------------
__global__ void gcn_scatter_kernel(const float* __restrict__ x,
                                   const int* __restrict__ edge_index,
                                   float* __restrict__ out, int n_edges) {
    int gid = blockIdx.x * blockDim.x + threadIdx.x;
    int e = gid >> 4;
    if (e >= n_edges) return;
    int j = (gid & 15) << 2;
    int src = edge_index[e];
    int dst = edge_index[n_edges + e];
    const float4 v = *(const float4*)(x + (size_t)src * DIM + j);
    float* o = out + (size_t)dst * DIM + j;
    atomicAdd(o + 0, v.x); atomicAdd(o + 1, v.y);
    atomicAdd(o + 2, v.z); atomicAdd(o + 3, v.w);
}

__global__ void gcn_linear_inplace_kernel(float* __restrict__ out,
                                          const float* __restrict__ W,
                                          const float* __restrict__ bias,
                                          int n_nodes) {
    __shared__ float Wt[DIM * DIM];
    __shared__ float rows[4][DIM];
    int tid = threadIdx.x;
    int col = tid & 63;
    int r = tid >> 6;
    for (int i = tid; i < DIM * DIM; i += 256) {
        int c = i >> 6, k = i & 63;
        Wt[k * DIM + c] = W[i];
    }
    int row = blockIdx.x * 4 + r;
    if (row < n_nodes) rows[r][col] = out[(size_t)row * DIM + col];
    __syncthreads();
    if (row < n_nodes) {
        float a = 0.f;
        #pragma unroll
        for (int k = 0; k < DIM; ++k) a += rows[r][k] * Wt[k * DIM + col];
        out[(size_t)row * DIM + col] = a + bias[col];
    }
}

// ===========================================================================
extern "C" void kernel_launch(void* const* d_in, const int* in_sizes, int n_in,
                              void* d_out, int out_size, void* d_ws, size_t ws_size,
                              hipStream_t stream) {
    const float* x          = (const float*)d_in[0];   // [N, 64]
    const float* W          = (const float*)d_in[1];   // [64, 64]
    const float* bias       = (const float*)d_in[2];   // [64]
    const int*   edge_index = (const int*)d_in[3];     // [2, E] (int32)

    const int E = in_sizes[3] / 2;
    const int N = in_sizes[0] / DIM;
    float* out = (float*)d_out;

    const int nb = (N + BN - 1) >> BN_SHIFT;

    // src-tile shift: smallest shift with (N-1)>>shift <= 15
    int shift = 0;
    while (((long long)(N - 1) >> shift) > 15) ++shift;

    auto align256 = [](size_t v) { return (v + 255) & ~(size_t)255; };
    const size_t xb_b   = align256(((size_t)N + 1) * DIM * 2);   // +1 zero row
    const size_t bin_b  = align256((size_t)nb * CAPE * 4);
    const size_t cnt_b  = align256(((size_t)nb + 64) * 4);       // gcnt + ovfcnt
    const size_t ovf_b  = align256((size_t)OVF_MAX * 2 * 4);
    const size_t needA = xb_b + bin_b + cnt_b + ovf_b;

    // src must fit in 26 bits for the (src<<6)|dstlo packing
    if (nb <= NB_MAX && N < (1 << 24) && ws_size >= needA) {
        char* p = (char*)d_ws;
        ushort4* xb4 = (ushort4*)p;          p += xb_b;
        int* binned  = (int*)p;              p += bin_b;
        int* gcnt    = (int*)p;              p += cnt_b;
        int* ovf     = (int*)p;
        int* ovfcnt  = gcnt + nb;            // adjacent -> one memset

        const int total4 = N * DIM / 4;

        hipMemsetAsync(gcnt, 0, cnt_b, stream);
        if ((long long)E <= (long long)PB * 1024 * KMAX) {
            fused_prep_reg_kernel<<<PB, 1024, 0, stream>>>(
                x, edge_index, xb4, gcnt, binned, ovf, ovfcnt, E, N, nb, total4);
        } else {
            fused_prep_kernel<<<PB, 1024, 0, stream>>>(
                x, edge_index, xb4, gcnt, binned, ovf, ovfcnt, E, N, nb, total4);
        }
        sort_gather_kernel<<<nb, 256, 0, stream>>>(
            (const unsigned short*)xb4, x, binned, gcnt, ovf, ovfcnt,
            W, bias, out, N, shift);
    } else {
        hipMemsetAsync(d_out, 0, (size_t)out_size * sizeof(float), stream);
        long long total = (long long)E * 16;
        int grid = (int)((total + 255) / 256);
        gcn_scatter_kernel<<<grid, 256, 0, stream>>>(x, edge_index, out, E);
        int lgrid = (N + 3) / 4;
        gcn_linear_inplace_kernel<<<lgrid, 256, 0, stream>>>(out, W, bias, N);
    }
}